// Round 4
// baseline (782.946 us; speedup 1.0000x reference)
//
#include <hip/hip_runtime.h>
#include <math.h>

#define NS   64
#define NOBS 10000
#define NB   256
#define TMAX 2048

// workspace layout (floats)
#define PIP_OFF 0
#define ASW_OFF 64                    // swizzled A_prob, 4096 floats
#define LSE_OFF (64 + 4096)
#define ET_OFF  (64 + 4096 + 64)
// total floats: 4224 + 640000 = 644224  (~2.58 MB)

__device__ __forceinline__ float wsum64(float v) {
  v += __shfl_xor(v, 1);
  v += __shfl_xor(v, 2);
  v += __shfl_xor(v, 4);
  v += __shfl_xor(v, 8);
  v += __shfl_xor(v, 16);
  v += __shfl_xor(v, 32);
  return v;
}

// DPP row_ror:N within 16-lane rows. Direction is NOT assumed — prep_small
// probes it and bakes the measured direction into the A swizzle.
#define DPPROR(S, N)                                                           \
  __int_as_float(__builtin_amdgcn_update_dpp(                                  \
      0, __float_as_int(S), 0x120 + (N), 0xF, 0xF, true))

// full xor-32 + xor-16 lane sum via gfx950 permlane swaps (VALU, no LDS).
// b-side goes through an opaque mov so the two swap operands are provably
// distinct physical registers. Parity of the swap pairing cancels (a=b).
#define COMB(Q) ({                                                             \
    float a32_ = (Q); float b32_;                                              \
    asm("v_mov_b32 %0, %1" : "=v"(b32_) : "v"(a32_));                          \
    asm("v_permlane32_swap_b32 %0, %1" : "+v"(a32_), "+v"(b32_));              \
    float s32_ = a32_ + b32_;                                                  \
    float a16_ = s32_; float b16_;                                             \
    asm("v_mov_b32 %0, %1" : "=v"(b16_) : "v"(s32_));                          \
    asm("v_permlane16_swap_b32 %0, %1" : "+v"(a16_), "+v"(b16_));              \
    a16_ + b16_; })

// ---------------- precompute: softmax(pi), column-softmax(A), swizzle ------
__global__ __launch_bounds__(64) void prep_small(const float* __restrict__ pi,
                                                 const float* __restrict__ A,
                                                 float* __restrict__ ws) {
  const int l = threadIdx.x;  // 0..63
  const int r = l & 15, c = l >> 4;
  float p = pi[l];
  float m = p;
  m = fmaxf(m, __shfl_xor(m, 1));
  m = fmaxf(m, __shfl_xor(m, 2));
  m = fmaxf(m, __shfl_xor(m, 4));
  m = fmaxf(m, __shfl_xor(m, 8));
  m = fmaxf(m, __shfl_xor(m, 16));
  m = fmaxf(m, __shfl_xor(m, 32));
  float ex = expf(p - m);
  float s = wsum64(ex);
  ws[PIP_OFF + l] = ex / s;

  // A column-softmax into LDS: lane l owns column l (softmax over axis=0)
  __shared__ float Ap[NS * NS];
  float cm = -3.0e38f;
  for (int i = 0; i < NS; ++i) cm = fmaxf(cm, A[i * NS + l]);
  float cs = 0.f;
  for (int i = 0; i < NS; ++i) cs += expf(A[i * NS + l] - cm);
  float inv = 1.0f / cs;
  for (int i = 0; i < NS; ++i) Ap[i * NS + l] = expf(A[i * NS + l] - cm) * inv;
  __syncthreads();

  // probe the hardware's row_ror direction: does lane l receive (l-1)&15 ?
  const int probe = __builtin_amdgcn_update_dpp(0, l, 0x121, 0xF, 0xF, true);
  const int dir = ((probe & 15) == ((r - 1) & 15)) ? 1 : -1;  // uniform

  // systolic swizzle matched to measured direction:
  // lane l=(r,c): aw[g][j] = Ap[r+16g][16c + ((r - dir*j)&15)]
  for (int g = 0; g < 4; ++g)
    for (int j = 0; j < 16; ++j)
      ws[ASW_OFF + l * 64 + g * 16 + j] =
          Ap[(r + 16 * g) * NS + (16 * c + ((r - dir * j) & 15))];
}

// ---------------- precompute: per-state emission logsumexp ----------------
__global__ __launch_bounds__(256) void emis_lse(const float* __restrict__ E,
                                                float* __restrict__ ws) {
  const int s = blockIdx.x;  // state
  const float* row = E + (size_t)s * NOBS;
  __shared__ float red[4];
  float m = -3.0e38f;
  for (int o = threadIdx.x; o < NOBS; o += 256) m = fmaxf(m, row[o]);
  m = fmaxf(m, __shfl_xor(m, 1));
  m = fmaxf(m, __shfl_xor(m, 2));
  m = fmaxf(m, __shfl_xor(m, 4));
  m = fmaxf(m, __shfl_xor(m, 8));
  m = fmaxf(m, __shfl_xor(m, 16));
  m = fmaxf(m, __shfl_xor(m, 32));
  const int wid = threadIdx.x >> 6;
  if ((threadIdx.x & 63) == 0) red[wid] = m;
  __syncthreads();
  m = fmaxf(fmaxf(red[0], red[1]), fmaxf(red[2], red[3]));
  __syncthreads();
  float sum = 0.f;
  for (int o = threadIdx.x; o < NOBS; o += 256) sum += expf(row[o] - m);
  sum = wsum64(sum);
  if ((threadIdx.x & 63) == 0) red[wid] = sum;
  __syncthreads();
  if (threadIdx.x == 0)
    ws[LSE_OFF + s] = m + logf(red[0] + red[1] + red[2] + red[3]);
}

// ---------------- precompute: EprobT[obs*64 + s] = exp(E[s,obs] - lse[s]) ----
__global__ __launch_bounds__(256) void emis_fill(const float* __restrict__ E,
                                                 float* __restrict__ ws) {
  const int idx = blockIdx.x * 256 + threadIdx.x;  // = obs*64 + s
  if (idx >= NS * NOBS) return;
  const int s = idx & 63;
  const int obs = idx >> 6;
  ws[ET_OFF + idx] = expf(E[(size_t)s * NOBS + obs] - ws[LSE_OFF + s]);
}

// ---------------- forward recursion: 1 batch = 1 block = 1 wave ----------------
// alpha in registers, canonical layout (lane i = alpha[i]). Per step: 15
// independent DPP rotations broadcast the 16 alphas of this lane's k-chunk,
// 64 VGPR fmas into 4 accumulators, permlane16/32 butterfly combine across
// k-chunks, 3 cndmasks re-canonicalize. Zero DS ops. Rescale (exact power-of-2
// bookkeeping) runs on the scalar pipe in parallel.
#define STEP(u, XSRC) do {                                                     \
    const int t_ = tb + j0 + (u);                                              \
    const float e_ = epf[(u)];                                                 \
    { const int obspf_ = __builtin_amdgcn_readlane((XSRC), (j0 + (u) + 8) & 63);\
      if (t_ + 8 < TMAX) epf[(u)] = ET[obspf_ * NS + lane]; }                  \
    const unsigned srf_ = __builtin_amdgcn_readfirstlane(__float_as_uint(s));  \
    const int se_ = (int)((srf_ >> 23) & 0xFFu) - 127;                         \
    const float sc_ = __uint_as_float((unsigned)(127 - se_) << 23);            \
    const float es_ = e_ * sc_;                                                \
    float rot[16];                                                             \
    rot[0] = s;                                                                \
    rot[1] = DPPROR(s, 1);   rot[2] = DPPROR(s, 2);   rot[3] = DPPROR(s, 3);   \
    rot[4] = DPPROR(s, 4);   rot[5] = DPPROR(s, 5);   rot[6] = DPPROR(s, 6);   \
    rot[7] = DPPROR(s, 7);   rot[8] = DPPROR(s, 8);   rot[9] = DPPROR(s, 9);   \
    rot[10] = DPPROR(s, 10); rot[11] = DPPROR(s, 11); rot[12] = DPPROR(s, 12); \
    rot[13] = DPPROR(s, 13); rot[14] = DPPROR(s, 14); rot[15] = DPPROR(s, 15); \
    float q0_ = 0.f, q1_ = 0.f, q2_ = 0.f, q3_ = 0.f;                          \
    _Pragma("unroll")                                                          \
    for (int j_ = 0; j_ < 16; ++j_) {                                          \
      q0_ = fmaf(aw[j_],      rot[j_], q0_);                                   \
      q1_ = fmaf(aw[16 + j_], rot[j_], q1_);                                   \
      q2_ = fmaf(aw[32 + j_], rot[j_], q2_);                                   \
      q3_ = fmaf(aw[48 + j_], rot[j_], q3_);                                   \
    }                                                                          \
    const float tot0_ = COMB(q0_);                                             \
    const float tot1_ = COMB(q1_);                                             \
    const float tot2_ = COMB(q2_);                                             \
    const float tot3_ = COMB(q3_);                                             \
    const float ta_ = (cgrp & 1) ? tot1_ : tot0_;                              \
    const float tb_ = (cgrp & 1) ? tot3_ : tot2_;                              \
    const float sel_ = (cgrp & 2) ? tb_ : ta_;                                 \
    const float w_ = es_ * ((t_ == 0) ? pip : sel_);                           \
    E2 += se_;                                                                 \
    if (t_ == Tn - 1) { vs = w_; e2s = E2; }                                   \
    s = w_;                                                                    \
  } while (0)

__global__ __launch_bounds__(64, 1) void hmm_fwd(const int* __restrict__ x,
                                                 const int* __restrict__ T,
                                                 const float* __restrict__ ws,
                                                 float* __restrict__ out) {
  const int lane = threadIdx.x;
  const int b = blockIdx.x;
  const int cgrp = lane >> 4;
  const float* __restrict__ ET = ws + ET_OFF;
  const int* __restrict__ xb = x + (size_t)b * TMAX;
  const int Tn = T[b];

  // swizzled A tile for this lane: aw[g*16+j], pinned into VGPRs
  float aw[NS];
  {
    const float4* ar = (const float4*)(ws + ASW_OFF + lane * NS);
#pragma unroll
    for (int q = 0; q < NS / 4; ++q) {
      float4 f = ar[q];
      aw[4 * q + 0] = f.x; aw[4 * q + 1] = f.y;
      aw[4 * q + 2] = f.z; aw[4 * q + 3] = f.w;
    }
  }
#pragma unroll
  for (int k = 0; k < NS; ++k) asm volatile("" : "+v"(aw[k]));  // no remat/sink

  const float pip = ws[PIP_OFF + lane];

  const int nch = (Tn + 63) >> 6;
  int xv = xb[lane];          // x chunk cc   (t in [64cc, 64cc+64))
  int xvn = xb[64 + lane];    // x chunk cc+1

  // emission prefetch pipeline, depth 8, statically indexed
  float epf[8];
#pragma unroll
  for (int u = 0; u < 8; ++u) {
    const int obs0 = __builtin_amdgcn_readlane(xv, u);
    epf[u] = ET[obs0 * NS + lane];
  }

  float s = 1.0f;   // exponent 0 -> se=0 at t=0
  float vs = 0.f;
  int E2 = 0, e2s = 0;

  for (int cc = 0; cc < nch; ++cc) {
    const int tb = cc << 6;
    for (int j0 = 0; j0 < 56; j0 += 8) {  // prefetch source: current chunk
      STEP(0, xv); STEP(1, xv); STEP(2, xv); STEP(3, xv);
      STEP(4, xv); STEP(5, xv); STEP(6, xv); STEP(7, xv);
    }
    {
      const int j0 = 56;                  // prefetch source: next chunk
      STEP(0, xvn); STEP(1, xvn); STEP(2, xvn); STEP(3, xvn);
      STEP(4, xvn); STEP(5, xvn); STEP(6, xvn); STEP(7, xvn);
    }
    xv = xvn;
    xvn = ((cc + 2) < (TMAX >> 6)) ? xb[((cc + 2) << 6) + lane] : 0;
  }

  const float sf = wsum64(vs);
  if (lane == 0) {
    const double lp = (double)logf(sf) + (double)e2s * 0.6931471805599453;
    out[b] = (float)lp;
  }
}

extern "C" void kernel_launch(void* const* d_in, const int* in_sizes, int n_in,
                              void* d_out, int out_size, void* d_ws, size_t ws_size,
                              hipStream_t stream) {
  const int*   x  = (const int*)d_in[0];
  const int*   T  = (const int*)d_in[1];
  const float* pi = (const float*)d_in[2];
  const float* A  = (const float*)d_in[3];
  const float* E  = (const float*)d_in[4];
  float* out = (float*)d_out;
  float* ws  = (float*)d_ws;

  prep_small<<<1, 64, 0, stream>>>(pi, A, ws);
  emis_lse<<<NS, 256, 0, stream>>>(E, ws);
  emis_fill<<<(NS * NOBS + 255) / 256, 256, 0, stream>>>(E, ws);
  hmm_fwd<<<NB, 64, 0, stream>>>(x, T, ws, out);
}

// Round 6
// 550.101 us; speedup vs baseline: 1.4233x; 1.4233x over previous
//
#include <hip/hip_runtime.h>
#include <math.h>

#define NS   64
#define NOBS 10000
#define NB   256
#define TMAX 2048

// workspace layout (floats)
#define PIP_OFF 0
#define ASW_OFF 64                    // swizzled A_prob, 4096 floats
#define LSE_OFF (64 + 4096)
#define ET_OFF  (64 + 4096 + 64)
// total floats: 4224 + 640000 = 644224  (~2.58 MB)

__device__ __forceinline__ float wsum64(float v) {
  v += __shfl_xor(v, 1);
  v += __shfl_xor(v, 2);
  v += __shfl_xor(v, 4);
  v += __shfl_xor(v, 8);
  v += __shfl_xor(v, 16);
  v += __shfl_xor(v, 32);
  return v;
}

// DPP row_ror:N within 16-lane rows. Direction is NOT assumed — prep_small
// probes it and bakes the measured direction into the A swizzle.
#define DPPROR(S, N)                                                           \
  __int_as_float(__builtin_amdgcn_update_dpp(                                  \
      0, __float_as_int(S), 0x120 + (N), 0xF, 0xF, true))

// full xor-32 + xor-16 lane sum via gfx950 permlane swaps (VALU, no LDS).
#define COMB(Q) ({                                                             \
    float a32_ = (Q); float b32_;                                              \
    asm("v_mov_b32 %0, %1" : "=v"(b32_) : "v"(a32_));                          \
    asm("v_permlane32_swap_b32 %0, %1" : "+v"(a32_), "+v"(b32_));              \
    float s32_ = a32_ + b32_;                                                  \
    float a16_ = s32_; float b16_;                                             \
    asm("v_mov_b32 %0, %1" : "=v"(b16_) : "v"(s32_));                          \
    asm("v_permlane16_swap_b32 %0, %1" : "+v"(a16_), "+v"(b16_));              \
    a16_ + b16_; })

// ---------------- precompute: softmax(pi), column-softmax(A), swizzle ------
__global__ __launch_bounds__(64) void prep_small(const float* __restrict__ pi,
                                                 const float* __restrict__ A,
                                                 float* __restrict__ ws) {
  const int l = threadIdx.x;  // 0..63
  const int r = l & 15, c = l >> 4;
  float p = pi[l];
  float m = p;
  m = fmaxf(m, __shfl_xor(m, 1));
  m = fmaxf(m, __shfl_xor(m, 2));
  m = fmaxf(m, __shfl_xor(m, 4));
  m = fmaxf(m, __shfl_xor(m, 8));
  m = fmaxf(m, __shfl_xor(m, 16));
  m = fmaxf(m, __shfl_xor(m, 32));
  float ex = expf(p - m);
  float s = wsum64(ex);
  ws[PIP_OFF + l] = ex / s;

  __shared__ float Ap[NS * NS];
  float cm = -3.0e38f;
  for (int i = 0; i < NS; ++i) cm = fmaxf(cm, A[i * NS + l]);
  float cs = 0.f;
  for (int i = 0; i < NS; ++i) cs += expf(A[i * NS + l] - cm);
  float inv = 1.0f / cs;
  for (int i = 0; i < NS; ++i) Ap[i * NS + l] = expf(A[i * NS + l] - cm) * inv;
  __syncthreads();

  // probe the hardware's row_ror direction: does lane l receive (l-1)&15 ?
  const int probe = __builtin_amdgcn_update_dpp(0, l, 0x121, 0xF, 0xF, true);
  const int dir = ((probe & 15) == ((r - 1) & 15)) ? 1 : -1;  // uniform

  // systolic swizzle matched to measured direction:
  // lane l=(r,c): aw[g][j] = Ap[r+16g][16c + ((r - dir*j)&15)]
  for (int g = 0; g < 4; ++g)
    for (int j = 0; j < 16; ++j)
      ws[ASW_OFF + l * 64 + g * 16 + j] =
          Ap[(r + 16 * g) * NS + (16 * c + ((r - dir * j) & 15))];
}

// ---------------- precompute: per-state emission logsumexp ----------------
__global__ __launch_bounds__(256) void emis_lse(const float* __restrict__ E,
                                                float* __restrict__ ws) {
  const int s = blockIdx.x;  // state
  const float* row = E + (size_t)s * NOBS;
  __shared__ float red[4];
  float m = -3.0e38f;
  for (int o = threadIdx.x; o < NOBS; o += 256) m = fmaxf(m, row[o]);
  m = fmaxf(m, __shfl_xor(m, 1));
  m = fmaxf(m, __shfl_xor(m, 2));
  m = fmaxf(m, __shfl_xor(m, 4));
  m = fmaxf(m, __shfl_xor(m, 8));
  m = fmaxf(m, __shfl_xor(m, 16));
  m = fmaxf(m, __shfl_xor(m, 32));
  const int wid = threadIdx.x >> 6;
  if ((threadIdx.x & 63) == 0) red[wid] = m;
  __syncthreads();
  m = fmaxf(fmaxf(red[0], red[1]), fmaxf(red[2], red[3]));
  __syncthreads();
  float sum = 0.f;
  for (int o = threadIdx.x; o < NOBS; o += 256) sum += expf(row[o] - m);
  sum = wsum64(sum);
  if ((threadIdx.x & 63) == 0) red[wid] = sum;
  __syncthreads();
  if (threadIdx.x == 0)
    ws[LSE_OFF + s] = m + logf(red[0] + red[1] + red[2] + red[3]);
}

// ---------------- precompute: EprobT[obs*64 + s] = exp(E[s,obs] - lse[s]) ----
__global__ __launch_bounds__(256) void emis_fill(const float* __restrict__ E,
                                                 float* __restrict__ ws) {
  const int idx = blockIdx.x * 256 + threadIdx.x;  // = obs*64 + s
  if (idx >= NS * NOBS) return;
  const int s = idx & 63;
  const int obs = idx >> 6;
  ws[ET_OFF + idx] = expf(E[(size_t)s * NOBS + obs] - ws[LSE_OFF + s]);
}

// ---------------- forward recursion: 1 batch = 1 block = 1 wave ----------------
// Emissions: whole 64-step chunk staged into LDS via global_load_lds (double
// buffer, ONE vmcnt(0) per chunk). Per-step e = ds_read_b32 issued 2 steps
// ahead (4-slot static rotation). Matvec: alpha in registers (lane i =
// alpha[i]), 15 DPP rotations + 64 VGPR fmas + permlane butterfly combine.
// amdgpu_waves_per_eu(1,1) pins occupancy to 1 wave/EU -> 512-VGPR budget so
// aw[64] stays resident (R1-R4 spilled it: 20KB/step scratch = 10.4GB FETCH).

#define PIN8(i)                                                                \
  asm volatile("" : "+v"(aw[(i)]), "+v"(aw[(i) + 1]), "+v"(aw[(i) + 2]),       \
                    "+v"(aw[(i) + 3]), "+v"(aw[(i) + 4]), "+v"(aw[(i) + 5]),   \
                    "+v"(aw[(i) + 6]), "+v"(aw[(i) + 7]))
#define PIN_AW() do { PIN8(0); PIN8(8); PIN8(16); PIN8(24);                    \
                      PIN8(32); PIN8(40); PIN8(48); PIN8(56); } while (0)

// stage 64 emission rows of a chunk (x values in XS) into half HALF of ebuf
#define STAGE_CHUNK(XS, HALF) do {                                             \
    _Pragma("unroll")                                                          \
    for (int k_ = 0; k_ < 64; ++k_) {                                          \
      const int xt_ = __builtin_amdgcn_readlane((XS), k_);                     \
      const float* gp_ = ET + ((size_t)(unsigned)xt_ << 6) + lane;             \
      __builtin_amdgcn_global_load_lds(gp_, &ebuf[(((HALF) << 6) + k_) << 6],  \
                                       4, 0, 0);                               \
    } } while (0)

#define STEP(u) do {                                                           \
    const int t_ = t0 + (u);                                                   \
    const float e_ = ee[(u)];                                                  \
    ee[((u) + 2) & 3] = ebuf[((t_ + 2) & 127) * 64 + lane];                    \
    const unsigned srf_ = __builtin_amdgcn_readfirstlane(__float_as_uint(s));  \
    const int se_ = (int)((srf_ >> 23) & 0xFFu) - 127;                         \
    const float sc_ = __uint_as_float((unsigned)(127 - se_) << 23);            \
    const float es_ = e_ * sc_;                                                \
    float rot[16];                                                             \
    rot[0] = s;                                                                \
    rot[1] = DPPROR(s, 1);   rot[2] = DPPROR(s, 2);   rot[3] = DPPROR(s, 3);   \
    rot[4] = DPPROR(s, 4);   rot[5] = DPPROR(s, 5);   rot[6] = DPPROR(s, 6);   \
    rot[7] = DPPROR(s, 7);   rot[8] = DPPROR(s, 8);   rot[9] = DPPROR(s, 9);   \
    rot[10] = DPPROR(s, 10); rot[11] = DPPROR(s, 11); rot[12] = DPPROR(s, 12); \
    rot[13] = DPPROR(s, 13); rot[14] = DPPROR(s, 14); rot[15] = DPPROR(s, 15); \
    float q0_ = 0.f, q1_ = 0.f, q2_ = 0.f, q3_ = 0.f;                          \
    _Pragma("unroll")                                                          \
    for (int j_ = 0; j_ < 16; ++j_) {                                          \
      q0_ = fmaf(aw[j_],      rot[j_], q0_);                                   \
      q1_ = fmaf(aw[16 + j_], rot[j_], q1_);                                   \
      q2_ = fmaf(aw[32 + j_], rot[j_], q2_);                                   \
      q3_ = fmaf(aw[48 + j_], rot[j_], q3_);                                   \
    }                                                                          \
    const float tot0_ = COMB(q0_);                                             \
    const float tot1_ = COMB(q1_);                                             \
    const float tot2_ = COMB(q2_);                                             \
    const float tot3_ = COMB(q3_);                                             \
    const float ta_ = (cgrp & 1) ? tot1_ : tot0_;                              \
    const float tb_ = (cgrp & 1) ? tot3_ : tot2_;                              \
    const float sel_ = (cgrp & 2) ? tb_ : ta_;                                 \
    const float w_ = es_ * ((t_ == 0) ? pip : sel_);                           \
    E2 += se_;                                                                 \
    if (t_ == Tn - 1) { vs = w_; e2s = E2; }                                   \
    s = w_;                                                                    \
  } while (0)

__global__ void __attribute__((amdgpu_flat_work_group_size(64, 64)))
__attribute__((amdgpu_waves_per_eu(1, 1)))
hmm_fwd(const int* __restrict__ x, const int* __restrict__ T,
        const float* __restrict__ ws, float* __restrict__ out) {
  const int lane = threadIdx.x;
  const int b = blockIdx.x;
  const int cgrp = lane >> 4;
  const float* __restrict__ ET = ws + ET_OFF;
  const int* __restrict__ xb = x + (size_t)b * TMAX;
  const int Tn = T[b];

  __shared__ __align__(16) float ebuf[128 * 64];  // 32 KB, 2 chunk halves

  // swizzled A tile for this lane: aw[g*16+j], pinned resident in VGPRs
  float aw[NS];
  {
    const float4* ar = (const float4*)(ws + ASW_OFF + lane * NS);
#pragma unroll
    for (int q = 0; q < 16; ++q) {
      float4 f = ar[q];
      aw[4 * q + 0] = f.x; aw[4 * q + 1] = f.y;
      aw[4 * q + 2] = f.z; aw[4 * q + 3] = f.w;
    }
  }
  PIN_AW();

  const float pip = ws[PIP_OFF + lane];

  // stage chunk 0, prime the e pipeline
  int xcur = xb[lane];
  STAGE_CHUNK(xcur, 0);
  int xnext = xb[64 + lane];
  asm volatile("s_waitcnt vmcnt(0)" ::: "memory");

  float ee[4];
  ee[0] = ebuf[0 * 64 + lane];
  ee[1] = ebuf[1 * 64 + lane];

  float s = 1.0f;   // exponent 0 -> se=0 at t=0
  float vs = 0.f;
  int E2 = 0, e2s = 0;

  const int nch = (Tn + 63) >> 6;
  for (int c = 0; c < nch; ++c) {
    const int tb = c << 6;
    if (c + 1 < TMAX / 64) STAGE_CHUNK(xnext, (c + 1) & 1);
    xnext = ((c + 2) < TMAX / 64) ? xb[((c + 2) << 6) + lane] : 0;
    for (int g = 0; g < 15; ++g) {      // t = tb .. tb+59
      const int t0 = tb + (g << 2);
      STEP(0); STEP(1); STEP(2); STEP(3);
    }
    // drain staging of chunk c+1 before lookahead reads cross the boundary
    asm volatile("s_waitcnt vmcnt(0)" ::: "memory");
    {
      const int t0 = tb + 60;           // t = tb+60 .. tb+63
      STEP(0); STEP(1); STEP(2); STEP(3);
    }
  }

  const float sf = wsum64(vs);
  if (lane == 0) {
    const double lp = (double)logf(sf) + (double)e2s * 0.6931471805599453;
    out[b] = (float)lp;
  }
}

extern "C" void kernel_launch(void* const* d_in, const int* in_sizes, int n_in,
                              void* d_out, int out_size, void* d_ws, size_t ws_size,
                              hipStream_t stream) {
  const int*   x  = (const int*)d_in[0];
  const int*   T  = (const int*)d_in[1];
  const float* pi = (const float*)d_in[2];
  const float* A  = (const float*)d_in[3];
  const float* E  = (const float*)d_in[4];
  float* out = (float*)d_out;
  float* ws  = (float*)d_ws;

  prep_small<<<1, 64, 0, stream>>>(pi, A, ws);
  emis_lse<<<NS, 256, 0, stream>>>(E, ws);
  emis_fill<<<(NS * NOBS + 255) / 256, 256, 0, stream>>>(E, ws);
  hmm_fwd<<<NB, 64, 0, stream>>>(x, T, ws, out);
}

// Round 7
// 462.248 us; speedup vs baseline: 1.6938x; 1.1901x over previous
//
#include <hip/hip_runtime.h>
#include <math.h>

#define NS   64
#define NOBS 10000
#define NB   256
#define TMAX 2048

// workspace layout (floats)
#define PIP_OFF 0
#define ASW_OFF 64                    // swizzled A_prob, 4096 floats
#define LSE_OFF (64 + 4096)
#define ET_OFF  (64 + 4096 + 64)

__device__ __forceinline__ float wsum64(float v) {
  v += __shfl_xor(v, 1);
  v += __shfl_xor(v, 2);
  v += __shfl_xor(v, 4);
  v += __shfl_xor(v, 8);
  v += __shfl_xor(v, 16);
  v += __shfl_xor(v, 32);
  return v;
}

// DPP row_ror:N within 16-lane rows. Direction probed at prep time.
#define DPPROR(S, N)                                                           \
  __int_as_float(__builtin_amdgcn_update_dpp(                                  \
      0, __float_as_int(S), 0x120 + (N), 0xF, 0xF, true))

// full xor-32 + xor-16 lane sum via gfx950 permlane swaps (parity-agnostic).
#define COMB(Q) ({                                                             \
    float a32_ = (Q); float b32_;                                              \
    asm("v_mov_b32 %0, %1" : "=v"(b32_) : "v"(a32_));                          \
    asm("v_permlane32_swap_b32 %0, %1" : "+v"(a32_), "+v"(b32_));              \
    float s32_ = a32_ + b32_;                                                  \
    float a16_ = s32_; float b16_;                                             \
    asm("v_mov_b32 %0, %1" : "=v"(b16_) : "v"(s32_));                          \
    asm("v_permlane16_swap_b32 %0, %1" : "+v"(a16_), "+v"(b16_));              \
    a16_ + b16_; })

// ---------------- precompute: softmax(pi), column-softmax(A), swizzle ------
__global__ __launch_bounds__(64) void prep_small(const float* __restrict__ pi,
                                                 const float* __restrict__ A,
                                                 float* __restrict__ ws) {
  const int l = threadIdx.x;  // 0..63
  const int r = l & 15, c = l >> 4;
  float p = pi[l];
  float m = p;
  m = fmaxf(m, __shfl_xor(m, 1));
  m = fmaxf(m, __shfl_xor(m, 2));
  m = fmaxf(m, __shfl_xor(m, 4));
  m = fmaxf(m, __shfl_xor(m, 8));
  m = fmaxf(m, __shfl_xor(m, 16));
  m = fmaxf(m, __shfl_xor(m, 32));
  float ex = expf(p - m);
  float s = wsum64(ex);
  ws[PIP_OFF + l] = ex / s;

  __shared__ float Ap[NS * NS];
  float cm = -3.0e38f;
  for (int i = 0; i < NS; ++i) cm = fmaxf(cm, A[i * NS + l]);
  float cs = 0.f;
  for (int i = 0; i < NS; ++i) cs += expf(A[i * NS + l] - cm);
  float inv = 1.0f / cs;
  for (int i = 0; i < NS; ++i) Ap[i * NS + l] = expf(A[i * NS + l] - cm) * inv;
  __syncthreads();

  // probe the hardware's row_ror direction: does lane l receive (l-1)&15 ?
  const int probe = __builtin_amdgcn_update_dpp(0, l, 0x121, 0xF, 0xF, true);
  const int dir = ((probe & 15) == ((r - 1) & 15)) ? 1 : -1;  // uniform

  // systolic swizzle matched to measured direction:
  for (int g = 0; g < 4; ++g)
    for (int j = 0; j < 16; ++j)
      ws[ASW_OFF + l * 64 + g * 16 + j] =
          Ap[(r + 16 * g) * NS + (16 * c + ((r - dir * j) & 15))];
}

// ---------------- precompute: per-state emission logsumexp ----------------
__global__ __launch_bounds__(256) void emis_lse(const float* __restrict__ E,
                                                float* __restrict__ ws) {
  const int s = blockIdx.x;  // state
  const float* row = E + (size_t)s * NOBS;
  __shared__ float red[4];
  float m = -3.0e38f;
  for (int o = threadIdx.x; o < NOBS; o += 256) m = fmaxf(m, row[o]);
  m = fmaxf(m, __shfl_xor(m, 1));
  m = fmaxf(m, __shfl_xor(m, 2));
  m = fmaxf(m, __shfl_xor(m, 4));
  m = fmaxf(m, __shfl_xor(m, 8));
  m = fmaxf(m, __shfl_xor(m, 16));
  m = fmaxf(m, __shfl_xor(m, 32));
  const int wid = threadIdx.x >> 6;
  if ((threadIdx.x & 63) == 0) red[wid] = m;
  __syncthreads();
  m = fmaxf(fmaxf(red[0], red[1]), fmaxf(red[2], red[3]));
  __syncthreads();
  float sum = 0.f;
  for (int o = threadIdx.x; o < NOBS; o += 256) sum += expf(row[o] - m);
  sum = wsum64(sum);
  if ((threadIdx.x & 63) == 0) red[wid] = sum;
  __syncthreads();
  if (threadIdx.x == 0)
    ws[LSE_OFF + s] = m + logf(red[0] + red[1] + red[2] + red[3]);
}

// ---------------- precompute: EprobT[obs*64 + s] = exp(E[s,obs] - lse[s]) ----
__global__ __launch_bounds__(256) void emis_fill(const float* __restrict__ E,
                                                 float* __restrict__ ws) {
  const int idx = blockIdx.x * 256 + threadIdx.x;  // = obs*64 + s
  if (idx >= NS * NOBS) return;
  const int s = idx & 63;
  const int obs = idx >> 6;
  ws[ET_OFF + idx] = expf(E[(size_t)s * NOBS + obs] - ws[LSE_OFF + s]);
}

// ---------------- forward recursion: 1 batch = 1 block = 1 wave ----------------
// Emissions: 64-step chunk staged into LDS via global_load_lds (double buffer,
// one hand-placed vmcnt(0) per chunk). Per 4-step group: 4 inline-asm
// ds_read_b32 (the ONLY lgkm ops in the loop) + exact s_waitcnt lgkmcnt(4) +
// sched_barrier(0). Matvec: alpha canonical in registers, 15 DPP rotations,
// 64 VGPR fmas (8 accumulators, depth-8 chains), permlane butterfly combine.

#define PIN8(i)                                                                \
  asm volatile("" : "+v"(aw[(i)]), "+v"(aw[(i) + 1]), "+v"(aw[(i) + 2]),       \
                    "+v"(aw[(i) + 3]), "+v"(aw[(i) + 4]), "+v"(aw[(i) + 5]),   \
                    "+v"(aw[(i) + 6]), "+v"(aw[(i) + 7]))
#define PIN_AW() do { PIN8(0); PIN8(8); PIN8(16); PIN8(24);                    \
                      PIN8(32); PIN8(40); PIN8(48); PIN8(56); } while (0)

// stage 64 emission rows of a chunk (x values in XS) into half HALF of ebuf
#define STAGE_CHUNK(XS, HALF) do {                                             \
    _Pragma("unroll")                                                          \
    for (int k_ = 0; k_ < 64; ++k_) {                                          \
      const int xt_ = __builtin_amdgcn_readlane((XS), k_);                     \
      const float* gp_ = ET + ((size_t)(unsigned)xt_ << 6) + lane;             \
      __builtin_amdgcn_global_load_lds(gp_, &ebuf[(((HALF) << 6) + k_) << 6],  \
                                       4, 0, 0);                               \
    } } while (0)

#define EREAD(DST, ADDR, IMM)                                                  \
  asm volatile("ds_read_b32 %0, %1 offset:" #IMM : "=v"(DST) : "v"(ADDR))

#define STEP(u, EC) do {                                                       \
    const int t_ = t0 + (u);                                                   \
    const float e_ = EC[(u)];                                                  \
    const unsigned srf_ = __builtin_amdgcn_readfirstlane(__float_as_uint(s));  \
    const int se_ = (int)((srf_ >> 23) & 0xFFu) - 127;                         \
    const float sc_ = __uint_as_float((unsigned)(127 - se_) << 23);            \
    const float es_ = e_ * sc_;                                                \
    float rot[16];                                                             \
    rot[0] = s;                                                                \
    rot[1] = DPPROR(s, 1);   rot[2] = DPPROR(s, 2);   rot[3] = DPPROR(s, 3);   \
    rot[4] = DPPROR(s, 4);   rot[5] = DPPROR(s, 5);   rot[6] = DPPROR(s, 6);   \
    rot[7] = DPPROR(s, 7);   rot[8] = DPPROR(s, 8);   rot[9] = DPPROR(s, 9);   \
    rot[10] = DPPROR(s, 10); rot[11] = DPPROR(s, 11); rot[12] = DPPROR(s, 12); \
    rot[13] = DPPROR(s, 13); rot[14] = DPPROR(s, 14); rot[15] = DPPROR(s, 15); \
    float q0a_ = 0.f, q1a_ = 0.f, q2a_ = 0.f, q3a_ = 0.f;                      \
    float q0b_ = 0.f, q1b_ = 0.f, q2b_ = 0.f, q3b_ = 0.f;                      \
    _Pragma("unroll")                                                          \
    for (int j_ = 0; j_ < 8; ++j_) {                                           \
      q0a_ = fmaf(aw[j_],      rot[j_], q0a_);                                 \
      q1a_ = fmaf(aw[16 + j_], rot[j_], q1a_);                                 \
      q2a_ = fmaf(aw[32 + j_], rot[j_], q2a_);                                 \
      q3a_ = fmaf(aw[48 + j_], rot[j_], q3a_);                                 \
      q0b_ = fmaf(aw[8 + j_],  rot[8 + j_], q0b_);                             \
      q1b_ = fmaf(aw[24 + j_], rot[8 + j_], q1b_);                             \
      q2b_ = fmaf(aw[40 + j_], rot[8 + j_], q2b_);                             \
      q3b_ = fmaf(aw[56 + j_], rot[8 + j_], q3b_);                             \
    }                                                                          \
    const float tot0_ = COMB(q0a_ + q0b_);                                     \
    const float tot1_ = COMB(q1a_ + q1b_);                                     \
    const float tot2_ = COMB(q2a_ + q2b_);                                     \
    const float tot3_ = COMB(q3a_ + q3b_);                                     \
    const float ta_ = (cgrp & 1) ? tot1_ : tot0_;                              \
    const float tb_ = (cgrp & 1) ? tot3_ : tot2_;                              \
    const float sel_ = (cgrp & 2) ? tb_ : ta_;                                 \
    const float w_ = es_ * ((t_ == 0) ? pip : sel_);                           \
    E2 += se_;                                                                 \
    if (t_ == Tn - 1) { vs = w_; e2s = E2; }                                   \
    s = w_;                                                                    \
  } while (0)

// one 4-step group: issue next group's 4 e-reads, exact-wait current's, run 4
#define GROUP(T0, ECUR, ENXT) do {                                             \
    const int t0 = (T0);                                                       \
    { const unsigned ea_ =                                                     \
          ebase + ((unsigned)(((t0 + 4) & 127)) << 8) + ((unsigned)lane << 2); \
      EREAD(ENXT[0], ea_, 0);   EREAD(ENXT[1], ea_, 256);                      \
      EREAD(ENXT[2], ea_, 512); EREAD(ENXT[3], ea_, 768); }                    \
    asm volatile("s_waitcnt lgkmcnt(4)");                                      \
    __builtin_amdgcn_sched_barrier(0);                                         \
    STEP(0, ECUR); STEP(1, ECUR); STEP(2, ECUR); STEP(3, ECUR);                \
  } while (0)

__global__ void __attribute__((amdgpu_flat_work_group_size(64, 64)))
__attribute__((amdgpu_waves_per_eu(1, 1)))
hmm_fwd(const int* __restrict__ x, const int* __restrict__ T,
        const float* __restrict__ ws, float* __restrict__ out) {
  const int lane = threadIdx.x;
  const int b = blockIdx.x;
  const int cgrp = lane >> 4;
  const float* __restrict__ ET = ws + ET_OFF;
  const int* __restrict__ xb = x + (size_t)b * TMAX;
  const int Tn = T[b];

  __shared__ __align__(16) float ebuf[128 * 64];  // 32 KB, 2 chunk halves
  const unsigned ebase = (unsigned)(size_t)ebuf;  // flat->LDS trunc (4GB-aligned aperture)

  // swizzled A tile for this lane: aw[g*16+j], pinned resident in VGPRs
  float aw[NS];
  {
    const float4* ar = (const float4*)(ws + ASW_OFF + lane * NS);
#pragma unroll
    for (int q = 0; q < 16; ++q) {
      float4 f = ar[q];
      aw[4 * q + 0] = f.x; aw[4 * q + 1] = f.y;
      aw[4 * q + 2] = f.z; aw[4 * q + 3] = f.w;
    }
  }
  PIN_AW();

  const float pip = ws[PIP_OFF + lane];

  // stage chunk 0, drain, prime group-0 e-reads
  int xcur = xb[lane];
  STAGE_CHUNK(xcur, 0);
  int xnext = xb[64 + lane];
  asm volatile("s_waitcnt vmcnt(0)" ::: "memory");

  float eA[4], eB[4];
  {
    const unsigned ea_ = ebase + ((unsigned)lane << 2);
    EREAD(eA[0], ea_, 0);   EREAD(eA[1], ea_, 256);
    EREAD(eA[2], ea_, 512); EREAD(eA[3], ea_, 768);
  }

  float s = 1.0f;   // exponent 0 -> se=0 at t=0
  float vs = 0.f;
  int E2 = 0, e2s = 0;

  const int nch = (Tn + 63) >> 6;
  for (int c = 0; c < nch; ++c) {
    const int tb = c << 6;
    if (c + 1 < TMAX / 64) STAGE_CHUNK(xnext, (c + 1) & 1);
    xnext = ((c + 2) < TMAX / 64) ? xb[((c + 2) << 6) + lane] : 0;
#pragma unroll 1
    for (int gp = 0; gp < 7; ++gp) {    // groups 0..13
      GROUP(tb + (gp << 3), eA, eB);
      GROUP(tb + (gp << 3) + 4, eB, eA);
    }
    GROUP(tb + 56, eA, eB);             // group 14
    // drain staging of chunk c+1 before group 15 issues next-chunk reads
    asm volatile("s_waitcnt vmcnt(0)" ::: "memory");
    GROUP(tb + 60, eB, eA);             // group 15 (loads eA for next chunk)
  }

  const float sf = wsum64(vs);
  if (lane == 0) {
    const double lp = (double)logf(sf) + (double)e2s * 0.6931471805599453;
    out[b] = (float)lp;
  }
}

extern "C" void kernel_launch(void* const* d_in, const int* in_sizes, int n_in,
                              void* d_out, int out_size, void* d_ws, size_t ws_size,
                              hipStream_t stream) {
  const int*   x  = (const int*)d_in[0];
  const int*   T  = (const int*)d_in[1];
  const float* pi = (const float*)d_in[2];
  const float* A  = (const float*)d_in[3];
  const float* E  = (const float*)d_in[4];
  float* out = (float*)d_out;
  float* ws  = (float*)d_ws;

  prep_small<<<1, 64, 0, stream>>>(pi, A, ws);
  emis_lse<<<NS, 256, 0, stream>>>(E, ws);
  emis_fill<<<(NS * NOBS + 255) / 256, 256, 0, stream>>>(E, ws);
  hmm_fwd<<<NB, 64, 0, stream>>>(x, T, ws, out);
}